// Round 5
// baseline (274.647 us; speedup 1.0000x reference)
//
#include <hip/hip_runtime.h>
#include <hip/hip_bf16.h>
#include <math.h>

// CRF loss on MI355X — LDS-staged GEMM frontend (R6).
//   k_prep:    W fp32->bf16 (pad 52->64), expT = exp(Tpad) bf16 [64][64], zero gold
//   k_scan:    512 blocks x 4 waves, 1 chunk/wave, 64 contiguous rows/block.
//              GEMM: block-cooperative A staging (global f32 -> regs -> bf16 LDS,
//              512B-contiguous row segments, double-buffered [64][132] bf16),
//              MFMA consumes A from LDS (2x ds_read_b64/kt), B from L2-hot wbf.
//              A-stage LDS is UNIONED with the scan's PT pool (phases disjoint).
//              Then: bf16 emit tile -> gold partial -> 16-step transfer-matrix
//              scan (wave-private, no barriers) -> bf16 chunk dump.
//   k_combine: 32 sequential 64x64 matvecs per batch, 4-deep register prefetch.
//
// Scan math: P <- diag(exp(emit_t - (7+r)ln2)) * exp(Tpad) * P; fixed 2^-7/step
// shift folded into exp arg + exact pow-2 rescale at t==7; integer exponent
// accumulated (cexp). Padding: Tpad[i][j>=52]=NEG (exp->0), Tpad[i>=52][j<52]=0.

#define NEGV   (-100000000.0f)
#define BB     64
#define TT     512
#define FF     1024
#define HH     52
#define HP     64
#define S_START 50
#define S_STOP  51
#define NCH    32            // chunks per batch
#define CLEN   (TT / NCH)    // 16 steps per chunk

typedef __bf16 bf16x8 __attribute__((ext_vector_type(8)));
typedef __bf16 bf16x4 __attribute__((ext_vector_type(4)));
typedef float  f32x4  __attribute__((ext_vector_type(4)));

// ---------------- ws layout (bytes) ----------------
#define WS_CHUNK  0u           // bf16 [2048][4096]               16,777,216
#define WS_CEXP   16777216u    // fp32 [2048]                          8,192
#define WS_WBF    16793600u    // bf16 [HP][FF]                      131,072
#define WS_EXPT   16924672u    // bf16 [64][64]                        8,192
#define WS_GOLD   16932864u    // fp32 [BB]                              256

#define ASTRIDE 132            // bf16 elements per staged A row (128 + 4 pad)

// ---- W fp32 -> bf16 (pad rows 52..63 = 0); block 0: gold=0 and expT ----
__global__ __launch_bounds__(256) void k_prep(const float* __restrict__ W,
                                              const float* __restrict__ trans,
                                              __bf16* __restrict__ wbf,
                                              __bf16* __restrict__ expT,
                                              float* __restrict__ gold) {
  int n = blockIdx.x;  // 0..63
  if (n == 0) {
    if (threadIdx.x < BB) gold[threadIdx.x] = 0.0f;
    for (int idx = threadIdx.x; idx < 4096; idx += 256) {
      int m = idx >> 6, k = idx & 63;
      float tv = (k >= HH) ? NEGV : ((m >= HH) ? 0.0f : trans[m * HH + k]);
      expT[idx] = (__bf16)__expf(tv);
    }
  }
  for (int k = threadIdx.x; k < FF; k += 256) {
    float v = (n < HH) ? W[n * FF + k] : 0.0f;
    wbf[n * FF + k] = (__bf16)v;
  }
}

// ---- fused GEMM (LDS-staged A) + gold + scan: 512 blocks x 4 waves ----
__global__ __launch_bounds__(256, 3) void k_scan(const float* __restrict__ feat,
                                                 const __bf16* __restrict__ wbf,
                                                 const __bf16* __restrict__ expT,
                                                 const float* __restrict__ bias,
                                                 const float* __restrict__ trans,
                                                 const float* __restrict__ masks,
                                                 const int* __restrict__ tags,
                                                 __bf16* __restrict__ chunks,
                                                 float* __restrict__ cexp,
                                                 float* __restrict__ gold) {
  const int tid = threadIdx.x;
  const int wv = tid >> 6;
  const int l  = tid & 63;
  const int lm = l & 15;
  const int q  = l >> 4;
  const int chunk = blockIdx.x * 4 + wv;   // 0..2047
  const int b = chunk >> 5, c = chunk & 31;

  // POOL: GEMM phase = A double-buffer 2x[64][132] bf16 (33,792 B);
  //       scan phase = 4x wave-private PT [64][72] bf16 (36,864 B).
  __shared__ __align__(16) __bf16 POOL[4 * 64 * 72];
  __shared__ __align__(16) __bf16 Eall[4][CLEN * 64];  // 8,192 B
  __bf16* el = Eall[wv];

  // ============ emit GEMM: M=64/block (16/wave), N=64, K=1024 ============
  // Block's A-tile rows are 64 CONTIGUOUS rows of feat.
  const float* fblock = feat + (size_t)(blockIdx.x * 64) * FF;
  // stage mapping: mega-step s covers k in [s*128, s*128+128).
  // instr j (0..7): row r = j*8 + (tid>>5), f32 col = (tid&31)*4
  //   -> each instruction = 8 rows x 512B contiguous segments.
  const int srow = tid >> 5;          // 0..7
  const int scol = (tid & 31) * 4;    // f32 col within 128-window
  __bf16* AS0 = POOL;
  __bf16* AS1 = POOL + 64 * ASTRIDE;

  f32x4 sreg[8];
  // prologue: stage s=0
#pragma unroll
  for (int j = 0; j < 8; ++j)
    sreg[j] = *(const f32x4*)(fblock + (size_t)(j * 8 + srow) * FF + scol);
#pragma unroll
  for (int j = 0; j < 8; ++j) {
    bf16x4 w;
#pragma unroll
    for (int i = 0; i < 4; ++i) w[i] = (__bf16)sreg[j][i];
    *(bf16x4*)&AS0[(j * 8 + srow) * ASTRIDE + scol] = w;
  }
  __syncthreads();

  bf16x8 bcur[4];
#pragma unroll
  for (int nt = 0; nt < 4; ++nt)
    bcur[nt] = *(const bf16x8*)(wbf + (size_t)(nt * 16 + lm) * FF + q * 8);

  f32x4 acc[4] = {};

#pragma unroll
  for (int s = 0; s < 8; ++s) {
    __bf16* cur = (s & 1) ? AS1 : AS0;
    __bf16* nxt = (s & 1) ? AS0 : AS1;
    if (s < 7) {
#pragma unroll
      for (int j = 0; j < 8; ++j)
        sreg[j] = *(const f32x4*)(fblock + (size_t)(j * 8 + srow) * FF + (s + 1) * 128 + scol);
    }
#pragma unroll
    for (int k2 = 0; k2 < 4; ++k2) {
      const int fk = s * 4 + k2;
      const __bf16* ap = &cur[(wv * 16 + lm) * ASTRIDE + k2 * 32 + q * 8];
      bf16x4 a0 = *(const bf16x4*)ap;
      bf16x4 a1 = *(const bf16x4*)(ap + 4);
      bf16x8 af;
      af[0] = a0[0]; af[1] = a0[1]; af[2] = a0[2]; af[3] = a0[3];
      af[4] = a1[0]; af[5] = a1[1]; af[6] = a1[2]; af[7] = a1[3];
      bf16x8 bnx[4];
      if (fk + 1 < 32) {
#pragma unroll
        for (int nt = 0; nt < 4; ++nt)
          bnx[nt] = *(const bf16x8*)(wbf + (size_t)(nt * 16 + lm) * FF + (fk + 1) * 32 + q * 8);
      }
#pragma unroll
      for (int nt = 0; nt < 4; ++nt)
        acc[nt] = __builtin_amdgcn_mfma_f32_16x16x32_bf16(af, bcur[nt], acc[nt], 0, 0, 0);
      if (fk + 1 < 32) {
#pragma unroll
        for (int nt = 0; nt < 4; ++nt) bcur[nt] = bnx[nt];
      }
    }
    if (s < 7) {
#pragma unroll
      for (int j = 0; j < 8; ++j) {
        bf16x4 w;
#pragma unroll
        for (int i = 0; i < 4; ++i) w[i] = (__bf16)sreg[j][i];
        *(bf16x4*)&nxt[(j * 8 + srow) * ASTRIDE + scol] = w;
      }
    }
    __syncthreads();
  }

  // epilogue -> LDS emit tile (bf16): el[t*64 + state]; D: row=q*4+rr, col=lm
#pragma unroll
  for (int nt = 0; nt < 4; ++nt) {
    int n = nt * 16 + lm;
    float bn = (n < HH) ? bias[n] : 0.0f;
#pragma unroll
    for (int rr = 0; rr < 4; ++rr)
      el[(q * 4 + rr) * 64 + n] = (__bf16)(acc[nt][rr] + bn);
  }

  // ================= gold partial for this chunk =================
  float mreg = (l < CLEN) ? masks[b * TT + c * CLEN + l] : 1.0f;
  int cur_t = (l < CLEN) ? tags[b * TT + c * CLEN + l] : 0;
  int prev = __shfl_up(cur_t, 1);
  if (l == 0) prev = (c == 0) ? S_START : tags[b * TT + c * CLEN - 1];
  float gp = 0.0f;
  if (l < CLEN) {
    float e  = (float)el[l * 64 + cur_t];
    float tr = trans[cur_t * HH + prev];
    gp = (e + tr) * mreg;
  }
#pragma unroll
  for (int d = 1; d < 64; d <<= 1) gp += __shfl_xor(gp, d);
  if (l == 0) atomicAdd(&gold[b], gp);

  // ================= scan (wave-private PT in POOL, no barriers) =================
  __bf16* pt = POOL + wv * (64 * 72);

  bf16x8 afrag[4][2];
#pragma unroll
  for (int mt = 0; mt < 4; ++mt)
#pragma unroll
    for (int kk = 0; kk < 2; ++kk)
      afrag[mt][kk] = *(const bf16x8*)&expT[(mt * 16 + lm) * 64 + kk * 32 + q * 8];

  // P = I (wave-private; in-order LDS -> no barriers)
  for (int idx = l; idx < 4096; idx += 64) {
    int n = idx >> 6, mm = idx & 63;
    pt[n * 72 + mm] = (__bf16)((n == mm) ? 1.0f : 0.0f);
  }

  int eacc = 0, rpend = 0;
  const float LOG2E = 1.4426950408889634f;

  for (int t = 0; t < CLEN; ++t) {
    float mcur = __shfl(mreg, t);             // wave-uniform
    if (mcur != 0.0f) {
      float sh = (float)(7 + rpend);
      eacc += 7 + rpend;
      rpend = 0;
      float s[4][4];
#pragma unroll
      for (int mt = 0; mt < 4; ++mt) {
        bf16x4 em4 = *(const bf16x4*)&el[t * 64 + mt * 16 + q * 4];
#pragma unroll
        for (int rr = 0; rr < 4; ++rr)
          s[mt][rr] = __builtin_amdgcn_exp2f(fmaf((float)em4[rr], LOG2E, -sh));
      }

      // ALL reads before ALL writes (in-order LDS per wave)
      bf16x8 bfr[2][4];
#pragma unroll
      for (int kk = 0; kk < 2; ++kk)
#pragma unroll
        for (int nt = 0; nt < 4; ++nt)
          bfr[kk][nt] = *(const bf16x8*)&pt[(nt * 16 + lm) * 72 + kk * 32 + q * 8];

      const bool trk = ((t & 7) == 7) && (t != CLEN - 1);
      float lmax = 0.0f;
      f32x4 zero = {};
#pragma unroll
      for (int mt = 0; mt < 4; ++mt) {
#pragma unroll
        for (int nt = 0; nt < 4; ++nt) {
          f32x4 a = __builtin_amdgcn_mfma_f32_16x16x32_bf16(afrag[mt][0], bfr[0][nt], zero, 0, 0, 0);
          a = __builtin_amdgcn_mfma_f32_16x16x32_bf16(afrag[mt][1], bfr[1][nt], a, 0, 0, 0);
          bf16x4 w4;
#pragma unroll
          for (int rr = 0; rr < 4; ++rr) {
            float v = a[rr] * s[mt][rr];
            if (trk) lmax = fmaxf(lmax, v);
            w4[rr] = (__bf16)v;
          }
          *(bf16x4*)&pt[(nt * 16 + lm) * 72 + mt * 16 + q * 4] = w4;
        }
      }
      if (trk) {
#pragma unroll
        for (int d = 1; d < 64; d <<= 1) lmax = fmaxf(lmax, __shfl_xor(lmax, d));
        if (lmax > 0.0f) rpend = ilogbf(lmax);
      }
    }
  }

  // dump (bf16, exact copy of pt values): cb[it*512 + l*8 + e] = P[it*8+e][l]
  __bf16* cb = chunks + (size_t)chunk * 4096;
#pragma unroll
  for (int it = 0; it < 8; ++it) {
    bf16x8 v;
#pragma unroll
    for (int e = 0; e < 8; ++e) v[e] = pt[(it * 8 + e) * 72 + l];
    *(bf16x8*)&cb[it * 512 + l * 8] = v;
  }
  if (l == 0) cexp[chunk] = (float)eacc;
}

// ---- combine: 64 blocks x 1 wave; 4-deep prefetch matvec chain (32 chunks) ----
__global__ __launch_bounds__(64) void k_combine(const __bf16* __restrict__ chunks,
                                                const float* __restrict__ cexp,
                                                const float* __restrict__ trans,
                                                const float* __restrict__ masks,
                                                const int* __restrict__ tags,
                                                const float* __restrict__ gold,
                                                float* __restrict__ out) {
  const int b = blockIdx.x;
  const int l = threadIdx.x;   // 0..63 = state i (row of M = output index)
  __shared__ __align__(16) float vsh[64];
  float v = (l == S_START) ? 1.0f : 0.0f;
  float esum = 0.0f;
  const float LN2 = 0.6931471805599453f;

  float msum = 0.0f;
  for (int t = l; t < TT; t += 64) msum += masks[b * TT + t];

  const __bf16* base = chunks + ((size_t)(b * NCH)) * 4096;

  // 4-deep register prefetch: pf[p][it] holds cols it*8..it*8+7 of row l.
  bf16x8 pf[4][8];
#pragma unroll
  for (int p = 0; p < 4; ++p)
#pragma unroll
    for (int it = 0; it < 8; ++it)
      pf[p][it] = *(const bf16x8*)&base[(size_t)p * 4096 + it * 512 + l * 8];

#pragma unroll
  for (int cc = 0; cc < NCH; ++cc) {
    vsh[l] = v;
    __syncthreads();
    float u = 0.0f;
#pragma unroll
    for (int it = 0; it < 8; ++it) {
      bf16x8 m8 = pf[cc & 3][it];
      f32x4 va = *(const f32x4*)&vsh[it * 8];
      f32x4 vb = *(const f32x4*)&vsh[it * 8 + 4];
      u += (float)m8[0] * va[0] + (float)m8[1] * va[1]
         + (float)m8[2] * va[2] + (float)m8[3] * va[3]
         + (float)m8[4] * vb[0] + (float)m8[5] * vb[1]
         + (float)m8[6] * vb[2] + (float)m8[7] * vb[3];
    }
    // issue prefetch for cc+4 into the slot just consumed
    if (cc + 4 < NCH) {
#pragma unroll
      for (int it = 0; it < 8; ++it)
        pf[cc & 3][it] = *(const bf16x8*)&base[(size_t)(cc + 4) * 4096 + it * 512 + l * 8];
    }
    esum += cexp[b * NCH + cc] * LN2;
    float mxx = u;
#pragma unroll
    for (int d = 1; d < 64; d <<= 1) mxx = fmaxf(mxx, __shfl_xor(mxx, d));
    if (mxx > 0.0f) {
      int ee = ilogbf(mxx);
      u = ldexpf(u, -ee);
      esum += (float)ee * LN2;
    }
    v = u;
    __syncthreads();
  }

  float ts = (l < HH) ? trans[S_STOP * HH + l] : NEGV;  // exp(NEG)=0 excludes pads
  float contrib = v * __expf(ts);
#pragma unroll
  for (int d = 1; d < 64; d <<= 1) {
    contrib += __shfl_xor(contrib, d);
    msum += __shfl_xor(msum, d);
  }
  if (l == 0) {
    int lp = (int)(msum + 0.5f);
    int lt = (lp == 0) ? S_START : tags[b * TT + lp - 1];
    float goldb = gold[b] + trans[S_STOP * HH + lt];
    float fwd = __logf(contrib) + esum;
    atomicAdd(out, (fwd - goldb) * (1.0f / 64.0f));
  }
}

extern "C" void kernel_launch(void* const* d_in, const int* in_sizes, int n_in,
                              void* d_out, int out_size, void* d_ws, size_t ws_size,
                              hipStream_t stream) {
  (void)in_sizes; (void)n_in; (void)out_size; (void)ws_size;
  const float* feat  = (const float*)d_in[0];
  const float* W     = (const float*)d_in[1];
  const float* bias  = (const float*)d_in[2];
  const float* trans = (const float*)d_in[3];
  const float* masks = (const float*)d_in[4];
  const int*   tags  = (const int*)d_in[5];

  char* ws = (char*)d_ws;
  __bf16* chunks = (__bf16*)(ws + WS_CHUNK);
  float*  cexp   = (float*)(ws + WS_CEXP);
  __bf16* wbf    = (__bf16*)(ws + WS_WBF);
  __bf16* expT   = (__bf16*)(ws + WS_EXPT);
  float*  gold   = (float*)(ws + WS_GOLD);

  hipMemsetAsync(d_out, 0, sizeof(float), stream);
  k_prep<<<HP, 256, 0, stream>>>(W, trans, wbf, expT, gold);
  k_scan<<<(BB * NCH) / 4, 256, 0, stream>>>(feat, wbf, expT, bias, trans, masks,
                                             tags, chunks, cexp, gold);
  k_combine<<<BB, 64, 0, stream>>>(chunks, cexp, trans, masks, tags, gold, (float*)d_out);
}

// Round 8
// 257.652 us; speedup vs baseline: 1.0660x; 1.0660x over previous
//
#include <hip/hip_runtime.h>
#include <hip/hip_bf16.h>
#include <math.h>

// CRF loss on MI355X — tree-combine version (R7).
//   k_prep: W fp32->bf16 (pad 52->64), expT = exp(Tpad) bf16 [64][64], zero gold
//   k_scan: (R2-measured 88us version, verbatim) per-wave fused emit GEMM +
//           gold partial + 16-step transfer-matrix scan -> bf16 chunk dump.
//   k_ga:   level-a combine: 256 blocks x 1 wave; each wave multiplies its
//           8 chunk matrices into one 64x64 group matrix G via MFMA (scan's
//           fragment pattern, wave-private LDS, NO barriers, no per-step
//           rescale -- one exact pow-2 normalize at dump). G stored in the
//           same layout as chunks; group exponent = sum(cexp)+ee.
//   k_gb:   level-b: 64 blocks x 1 wave; only 4 matvec links, all G
//           preloaded to registers, NO __syncthreads (wave-private LDS in
//           program order -> no forced vmcnt(0) drains) + final terms.
//
// Scan math: P <- diag(exp(emit_t - (7+r)ln2)) * exp(Tpad) * P; fixed 2^-7/step
// shift folded into exp arg + exact pow-2 rescale at t==7; integer exponent in
// cexp. Padding: Tpad[i][j>=52]=NEG (exp->0), Tpad[i>=52][j<52]=0.
// Chunk layout: cb[(j>>3)*512 + i*8 + (j&7)] = P[i][j]  (G uses the same).

#define NEGV   (-100000000.0f)
#define BB     64
#define TT     512
#define FF     1024
#define HH     52
#define HP     64
#define S_START 50
#define S_STOP  51
#define NCH    32            // chunks per batch
#define CLEN   (TT / NCH)    // 16 steps per chunk
#define GRP    8             // chunks per group
#define NGRP   (NCH / GRP)   // 4 groups per batch

typedef __bf16 bf16x8 __attribute__((ext_vector_type(8)));
typedef __bf16 bf16x4 __attribute__((ext_vector_type(4)));
typedef float  f32x4  __attribute__((ext_vector_type(4)));

// ---------------- ws layout (bytes) ----------------
#define WS_CHUNK  0u           // bf16 [2048][4096]               16,777,216
#define WS_CEXP   16777216u    // fp32 [2048]                          8,192
#define WS_GBUF   16785408u    // bf16 [256][4096]                 2,097,152
#define WS_GCEXP  18882560u    // fp32 [256]                           1,024
#define WS_WBF    18883584u    // bf16 [HP][FF]                      131,072
#define WS_EXPT   19014656u    // bf16 [64][64]                        8,192
#define WS_GOLD   19022848u    // fp32 [BB]                              256

// ---- W fp32 -> bf16 (pad rows 52..63 = 0); block 0: gold=0 and expT ----
__global__ __launch_bounds__(256) void k_prep(const float* __restrict__ W,
                                              const float* __restrict__ trans,
                                              __bf16* __restrict__ wbf,
                                              __bf16* __restrict__ expT,
                                              float* __restrict__ gold) {
  int n = blockIdx.x;  // 0..63
  if (n == 0) {
    if (threadIdx.x < BB) gold[threadIdx.x] = 0.0f;
    for (int idx = threadIdx.x; idx < 4096; idx += 256) {
      int m = idx >> 6, k = idx & 63;
      float tv = (k >= HH) ? NEGV : ((m >= HH) ? 0.0f : trans[m * HH + k]);
      expT[idx] = (__bf16)__expf(tv);
    }
  }
  for (int k = threadIdx.x; k < FF; k += 256) {
    float v = (n < HH) ? W[n * FF + k] : 0.0f;
    wbf[n * FF + k] = (__bf16)v;
  }
}

// ---- fused GEMM + gold partial + scan: 512 blocks x 4 waves (R2-measured) ----
__global__ __launch_bounds__(256, 2) void k_scan(const float* __restrict__ feat,
                                                 const __bf16* __restrict__ wbf,
                                                 const __bf16* __restrict__ expT,
                                                 const float* __restrict__ bias,
                                                 const float* __restrict__ trans,
                                                 const float* __restrict__ masks,
                                                 const int* __restrict__ tags,
                                                 __bf16* __restrict__ chunks,
                                                 float* __restrict__ cexp,
                                                 float* __restrict__ gold) {
  const int tid = threadIdx.x;
  const int wv = tid >> 6;
  const int l  = tid & 63;
  const int lm = l & 15;
  const int q  = l >> 4;
  const int chunk = blockIdx.x * 4 + wv;   // 0..2047
  const int b = chunk >> 5, c = chunk & 31;

  __shared__ __align__(16) __bf16 PTall[4][64 * 72];   // 36,864 B
  __shared__ __align__(16) __bf16 Eall[4][CLEN * 64];  //  8,192 B
  __bf16* pt = PTall[wv];
  __bf16* el = Eall[wv];

  // ================= emit GEMM: M=16 (t), N=64 (state), K=1024 =================
  const float* fbase = feat + ((size_t)(b * TT + c * CLEN)) * FF;
  const float* arow  = fbase + (size_t)lm * FF + q * 8;

  // A prefetch, 4 k-chunks deep (32 B/lane per k-chunk)
  f32x4 apre[4][2];
#pragma unroll
  for (int s = 0; s < 4; ++s)
#pragma unroll
    for (int h = 0; h < 2; ++h)
      apre[s][h] = *(const f32x4*)(arow + s * 32 + h * 4);

  bf16x8 bcur[4];
#pragma unroll
  for (int nt = 0; nt < 4; ++nt)
    bcur[nt] = *(const bf16x8*)(wbf + (size_t)(nt * 16 + lm) * FF + q * 8);

  f32x4 acc[4] = {};

#pragma unroll
  for (int kt = 0; kt < 32; ++kt) {
    const int st = kt & 3;
    bf16x8 af;
#pragma unroll
    for (int j = 0; j < 4; ++j) {
      af[j]     = (__bf16)apre[st][0][j];
      af[4 + j] = (__bf16)apre[st][1][j];
    }
    if (kt + 4 < 32) {
#pragma unroll
      for (int h = 0; h < 2; ++h)
        apre[st][h] = *(const f32x4*)(arow + (kt + 4) * 32 + h * 4);
    }
    bf16x8 bnx[4];
    if (kt + 1 < 32) {
#pragma unroll
      for (int nt = 0; nt < 4; ++nt)
        bnx[nt] = *(const bf16x8*)(wbf + (size_t)(nt * 16 + lm) * FF + (kt + 1) * 32 + q * 8);
    }
#pragma unroll
    for (int nt = 0; nt < 4; ++nt)
      acc[nt] = __builtin_amdgcn_mfma_f32_16x16x32_bf16(af, bcur[nt], acc[nt], 0, 0, 0);
    if (kt + 1 < 32) {
#pragma unroll
      for (int nt = 0; nt < 4; ++nt) bcur[nt] = bnx[nt];
    }
  }

  // epilogue -> LDS emit tile (bf16): el[t*64 + state]; D: row=q*4+rr, col=lm
#pragma unroll
  for (int nt = 0; nt < 4; ++nt) {
    int n = nt * 16 + lm;
    float bn = (n < HH) ? bias[n] : 0.0f;
#pragma unroll
    for (int rr = 0; rr < 4; ++rr)
      el[(q * 4 + rr) * 64 + n] = (__bf16)(acc[nt][rr] + bn);
  }

  // ================= gold partial for this chunk =================
  float mreg = (l < CLEN) ? masks[b * TT + c * CLEN + l] : 1.0f;
  int cur = (l < CLEN) ? tags[b * TT + c * CLEN + l] : 0;
  int prev = __shfl_up(cur, 1);
  if (l == 0) prev = (c == 0) ? S_START : tags[b * TT + c * CLEN - 1];
  float gp = 0.0f;
  if (l < CLEN) {
    float e  = (float)el[l * 64 + cur];
    float tr = trans[cur * HH + prev];
    gp = (e + tr) * mreg;
  }
#pragma unroll
  for (int d = 1; d < 64; d <<= 1) gp += __shfl_xor(gp, d);
  if (l == 0) atomicAdd(&gold[b], gp);

  // ================= scan =================
  bf16x8 afrag[4][2];
#pragma unroll
  for (int mt = 0; mt < 4; ++mt)
#pragma unroll
    for (int kk = 0; kk < 2; ++kk)
      afrag[mt][kk] = *(const bf16x8*)&expT[(mt * 16 + lm) * 64 + kk * 32 + q * 8];

  // P = I (wave-private; in-order LDS -> no barriers)
  for (int idx = l; idx < 4096; idx += 64) {
    int n = idx >> 6, mm = idx & 63;
    pt[n * 72 + mm] = (__bf16)((n == mm) ? 1.0f : 0.0f);
  }

  int eacc = 0, rpend = 0;
  const float LOG2E = 1.4426950408889634f;

  for (int t = 0; t < CLEN; ++t) {
    float mcur = __shfl(mreg, t);             // wave-uniform
    if (mcur != 0.0f) {
      float sh = (float)(7 + rpend);
      eacc += 7 + rpend;
      rpend = 0;
      float s[4][4];
#pragma unroll
      for (int mt = 0; mt < 4; ++mt) {
        bf16x4 em4 = *(const bf16x4*)&el[t * 64 + mt * 16 + q * 4];
#pragma unroll
        for (int rr = 0; rr < 4; ++rr)
          s[mt][rr] = __builtin_amdgcn_exp2f(fmaf((float)em4[rr], LOG2E, -sh));
      }

      // ALL reads before ALL writes (in-order LDS per wave)
      bf16x8 bfr[2][4];
#pragma unroll
      for (int kk = 0; kk < 2; ++kk)
#pragma unroll
        for (int nt = 0; nt < 4; ++nt)
          bfr[kk][nt] = *(const bf16x8*)&pt[(nt * 16 + lm) * 72 + kk * 32 + q * 8];

      const bool trk = ((t & 7) == 7) && (t != CLEN - 1);
      float lmax = 0.0f;
      f32x4 zero = {};
#pragma unroll
      for (int mt = 0; mt < 4; ++mt) {
#pragma unroll
        for (int nt = 0; nt < 4; ++nt) {
          f32x4 a = __builtin_amdgcn_mfma_f32_16x16x32_bf16(afrag[mt][0], bfr[0][nt], zero, 0, 0, 0);
          a = __builtin_amdgcn_mfma_f32_16x16x32_bf16(afrag[mt][1], bfr[1][nt], a, 0, 0, 0);
          bf16x4 w4;
#pragma unroll
          for (int rr = 0; rr < 4; ++rr) {
            float v = a[rr] * s[mt][rr];
            if (trk) lmax = fmaxf(lmax, v);
            w4[rr] = (__bf16)v;
          }
          *(bf16x4*)&pt[(nt * 16 + lm) * 72 + mt * 16 + q * 4] = w4;
        }
      }
      if (trk) {
#pragma unroll
        for (int d = 1; d < 64; d <<= 1) lmax = fmaxf(lmax, __shfl_xor(lmax, d));
        if (lmax > 0.0f) rpend = ilogbf(lmax);
      }
    }
  }

  // dump: cb[it*512 + l*8 + e] = P[i=l][j=it*8+e]
  __bf16* cb = chunks + (size_t)chunk * 4096;
#pragma unroll
  for (int it = 0; it < 8; ++it) {
    bf16x8 v;
#pragma unroll
    for (int e = 0; e < 8; ++e) v[e] = pt[(it * 8 + e) * 72 + l];
    *(bf16x8*)&cb[it * 512 + l * 8] = v;
  }
  if (l == 0) cexp[chunk] = (float)eacc;
}

// ---- level-a combine: 256 blocks x 1 wave; G = M7*...*M0 per group (MFMA) ----
__global__ __launch_bounds__(64) void k_ga(const __bf16* __restrict__ chunks,
                                           const float* __restrict__ cexp,
                                           __bf16* __restrict__ gbuf,
                                           float* __restrict__ gcexp) {
  const int g  = blockIdx.x;          // 0..255
  const int b  = g >> 2, qq = g & 3;
  const int l  = threadIdx.x;         // 0..63
  const int lm = l & 15;
  const int q  = l >> 4;

  __shared__ __align__(16) __bf16 ptq[64 * 72];   // Q transposed: ptq[j][i]=Q[i][j]
  const __bf16* mbase = chunks + ((size_t)(b * NCH + qq * GRP)) * 4096;

  // init Q = M0 (transpose chunk layout into ptq; wave-private, in-order)
#pragma unroll
  for (int it = 0; it < 8; ++it) {
    bf16x8 mv = *(const bf16x8*)&mbase[it * 512 + l * 8];   // M0[l][it*8+e]
#pragma unroll
    for (int e = 0; e < 8; ++e) ptq[(it * 8 + e) * 72 + l] = mv[e];
  }

  // 7 left-multiplies: Q <- Mj * Q  (no per-step rescale; bf16 range absorbs)
#pragma unroll
  for (int j = 1; j < GRP; ++j) {
    const __bf16* mj = mbase + (size_t)j * 4096;
    bf16x8 af[4][2];
#pragma unroll
    for (int mt = 0; mt < 4; ++mt)
#pragma unroll
      for (int kk = 0; kk < 2; ++kk)
        af[mt][kk] = *(const bf16x8*)&mj[(kk * 4 + q) * 512 + (mt * 16 + lm) * 8];
    bf16x8 bfr[2][4];
#pragma unroll
    for (int kk = 0; kk < 2; ++kk)
#pragma unroll
      for (int nt = 0; nt < 4; ++nt)
        bfr[kk][nt] = *(const bf16x8*)&ptq[(nt * 16 + lm) * 72 + kk * 32 + q * 8];
    f32x4 zero = {};
#pragma unroll
    for (int mt = 0; mt < 4; ++mt) {
#pragma unroll
      for (int nt = 0; nt < 4; ++nt) {
        f32x4 a = __builtin_amdgcn_mfma_f32_16x16x32_bf16(af[mt][0], bfr[0][nt], zero, 0, 0, 0);
        a = __builtin_amdgcn_mfma_f32_16x16x32_bf16(af[mt][1], bfr[1][nt], a, 0, 0, 0);
        bf16x4 w4;
#pragma unroll
        for (int rr = 0; rr < 4; ++rr) w4[rr] = (__bf16)a[rr];
        *(bf16x4*)&ptq[(nt * 16 + lm) * 72 + mt * 16 + q * 4] = w4;
      }
    }
  }

  // normalize (exact pow-2) + dump in chunk layout
  float vals[8][8];
  float lmax = 0.0f;
#pragma unroll
  for (int it = 0; it < 8; ++it)
#pragma unroll
    for (int e = 0; e < 8; ++e) {
      float x = (float)ptq[(it * 8 + e) * 72 + l];    // Q[l][it*8+e]
      vals[it][e] = x;
      lmax = fmaxf(lmax, x);
    }
#pragma unroll
  for (int d = 1; d < 64; d <<= 1) lmax = fmaxf(lmax, __shfl_xor(lmax, d));
  int ee = (lmax > 0.0f) ? ilogbf(lmax) : 0;
  float sc = ldexpf(1.0f, -ee);
  __bf16* gb = gbuf + (size_t)g * 4096;
#pragma unroll
  for (int it = 0; it < 8; ++it) {
    bf16x8 w;
#pragma unroll
    for (int e = 0; e < 8; ++e) w[e] = (__bf16)(vals[it][e] * sc);
    *(bf16x8*)&gb[it * 512 + l * 8] = w;
  }
  if (l == 0) {
    float s = (float)ee;
#pragma unroll
    for (int c = 0; c < GRP; ++c) s += cexp[b * NCH + qq * GRP + c];
    gcexp[g] = s;
  }
}

// ---- level-b: 64 blocks x 1 wave; 4-link matvec chain, NO barriers ----
__global__ __launch_bounds__(64) void k_gb(const __bf16* __restrict__ gbuf,
                                           const float* __restrict__ gcexp,
                                           const float* __restrict__ trans,
                                           const float* __restrict__ masks,
                                           const int* __restrict__ tags,
                                           const float* __restrict__ gold,
                                           float* __restrict__ out) {
  const int b = blockIdx.x;
  const int l = threadIdx.x;   // 0..63 = state i (row of G)
  __shared__ __align__(16) float vsh[64];
  float v = (l == S_START) ? 1.0f : 0.0f;
  float esum = 0.0f;
  const float LN2 = 0.6931471805599453f;

  float msum = 0.0f;
  for (int t = l; t < TT; t += 64) msum += masks[b * TT + t];

  // preload ALL 4 group matrices (row l, all cols)
  bf16x8 pf[NGRP][8];
#pragma unroll
  for (int p = 0; p < NGRP; ++p)
#pragma unroll
    for (int it = 0; it < 8; ++it)
      pf[p][it] = *(const bf16x8*)&gbuf[((size_t)(b * NGRP + p)) * 4096 + it * 512 + l * 8];

#pragma unroll
  for (int g = 0; g < NGRP; ++g) {
    vsh[l] = v;                 // wave-private LDS, program order -> no barrier
    float u = 0.0f;
#pragma unroll
    for (int it = 0; it < 8; ++it) {
      bf16x8 m8 = pf[g][it];
      f32x4 va = *(const f32x4*)&vsh[it * 8];
      f32x4 vb = *(const f32x4*)&vsh[it * 8 + 4];
      u += (float)m8[0] * va[0] + (float)m8[1] * va[1]
         + (float)m8[2] * va[2] + (float)m8[3] * va[3]
         + (float)m8[4] * vb[0] + (float)m8[5] * vb[1]
         + (float)m8[6] * vb[2] + (float)m8[7] * vb[3];
    }
    esum += gcexp[b * NGRP + g] * LN2;
    float mxx = u;
#pragma unroll
    for (int d = 1; d < 64; d <<= 1) mxx = fmaxf(mxx, __shfl_xor(mxx, d));
    if (mxx > 0.0f) {
      int ee = ilogbf(mxx);
      u = ldexpf(u, -ee);
      esum += (float)ee * LN2;
    }
    v = u;
  }

  float ts = (l < HH) ? trans[S_STOP * HH + l] : NEGV;  // exp(NEG)=0 excludes pads
  float contrib = v * __expf(ts);
#pragma unroll
  for (int d = 1; d < 64; d <<= 1) {
    contrib += __shfl_xor(contrib, d);
    msum += __shfl_xor(msum, d);
  }
  if (l == 0) {
    int lp = (int)(msum + 0.5f);
    int lt = (lp == 0) ? S_START : tags[b * TT + lp - 1];
    float goldb = gold[b] + trans[S_STOP * HH + lt];
    float fwd = __logf(contrib) + esum;
    atomicAdd(out, (fwd - goldb) * (1.0f / 64.0f));
  }
}

extern "C" void kernel_launch(void* const* d_in, const int* in_sizes, int n_in,
                              void* d_out, int out_size, void* d_ws, size_t ws_size,
                              hipStream_t stream) {
  (void)in_sizes; (void)n_in; (void)out_size; (void)ws_size;
  const float* feat  = (const float*)d_in[0];
  const float* W     = (const float*)d_in[1];
  const float* bias  = (const float*)d_in[2];
  const float* trans = (const float*)d_in[3];
  const float* masks = (const float*)d_in[4];
  const int*   tags  = (const int*)d_in[5];

  char* ws = (char*)d_ws;
  __bf16* chunks = (__bf16*)(ws + WS_CHUNK);
  float*  cexp   = (float*)(ws + WS_CEXP);
  __bf16* gbuf   = (__bf16*)(ws + WS_GBUF);
  float*  gcexp  = (float*)(ws + WS_GCEXP);
  __bf16* wbf    = (__bf16*)(ws + WS_WBF);
  __bf16* expT   = (__bf16*)(ws + WS_EXPT);
  float*  gold   = (float*)(ws + WS_GOLD);

  hipMemsetAsync(d_out, 0, sizeof(float), stream);
  k_prep<<<HP, 256, 0, stream>>>(W, trans, wbf, expT, gold);
  k_scan<<<(BB * NCH) / 4, 256, 0, stream>>>(feat, wbf, expT, bias, trans, masks,
                                             tags, chunks, cexp, gold);
  k_ga<<<BB * NGRP, 64, 0, stream>>>(chunks, cexp, gbuf, gcexp);
  k_gb<<<BB, 64, 0, stream>>>(gbuf, gcexp, trans, masks, tags, gold, (float*)d_out);
}